// Round 10
// baseline (189.751 us; speedup 1.0000x reference)
//
#include <hip/hip_runtime.h>
#include <hip/hip_bf16.h>
#include <cstdint>
#include <cstddef>

typedef __bf16 bf16_t;
typedef bf16_t bf16x8 __attribute__((ext_vector_type(8)));
typedef bf16_t bf16x4 __attribute__((ext_vector_type(4)));
typedef bf16_t bf16x2 __attribute__((ext_vector_type(2)));
typedef float f32x4 __attribute__((ext_vector_type(4)));
typedef float f32x16 __attribute__((ext_vector_type(16)));
typedef unsigned int u32x4 __attribute__((ext_vector_type(4)));

namespace {
constexpr int Bv = 2, Lv = 2048, Ev = 1024, NHv = 16;
constexpr int Mv = Bv * Lv;  // 4096
constexpr float SCALE_L2E = 0.03125f * 1.4426950408889634f;  // (1/sqrt(1024)) * log2(e)
}

__device__ __forceinline__ void gload_lds16(const void* g, void* l) {
  __builtin_amdgcn_global_load_lds(
      (const __attribute__((address_space(1))) unsigned int*)g,
      (__attribute__((address_space(3))) unsigned int*)l,
      16, 0, 0);
}

// ---------- elementwise f32 -> bf16 (two tensors via z) ----------
__global__ __launch_bounds__(256) void k_cvt2(const float* __restrict__ x0,
                                              const float* __restrict__ x1,
                                              bf16_t* __restrict__ y0,
                                              bf16_t* __restrict__ y1, int n4) {
  const float* x = blockIdx.z ? x1 : x0;
  bf16_t* y = blockIdx.z ? y1 : y0;
  int i = blockIdx.x * 256 + threadIdx.x;
  if (i < n4) {
    float4 v = reinterpret_cast<const float4*>(x)[i];
    bf16x4 o = {(bf16_t)v.x, (bf16_t)v.y, (bf16_t)v.z, (bf16_t)v.w};
    *reinterpret_cast<bf16x4*>(&y[(size_t)i * 4]) = o;
  }
}

// ---------- transpose 4 weight matrices 1024x1024 f32 -> bf16 [N][K] ----------
__global__ __launch_bounds__(256) void k_twt(const float* w0, const float* w1,
                                             const float* w2, const float* w3,
                                             bf16_t* t0, bf16_t* t1,
                                             bf16_t* t2, bf16_t* t3) {
  const float* W;
  bf16_t* T;
  switch (blockIdx.z) {
    case 0: W = w0; T = t0; break;
    case 1: W = w1; T = t1; break;
    case 2: W = w2; T = t2; break;
    default: W = w3; T = t3; break;
  }
  __shared__ float tile[32][33];
  const int tx = threadIdx.x, ty = threadIdx.y;  // (32,8)
  const int n0 = blockIdx.x * 32, k0 = blockIdx.y * 32;
#pragma unroll
  for (int i = 0; i < 4; i++) {
    int r = ty + i * 8;
    tile[r][tx] = W[(size_t)(k0 + r) * Ev + n0 + tx];
  }
  __syncthreads();
#pragma unroll
  for (int i = 0; i < 4; i++) {
    int r = ty + i * 8;
    T[(size_t)(n0 + r) * Ev + k0 + tx] = (bf16_t)tile[tx][r];
  }
}

// ---------- RoPE trig table: tab[l*16+i] = {cos, sin}(l * 10000^(-i/16)) ----------
__global__ __launch_bounds__(256) void k_trig(float2* __restrict__ tab) {
  int t = blockIdx.x * 256 + threadIdx.x;  // 2048*16
  int i = t & 15, l = t >> 4;
  float inv = exp2f(-13.287712379549449f * (float)i * (1.0f / 16.0f));
  float s, c;
  sincosf((float)l * inv, &s, &c);
  tab[t] = make_float2(c, s);
}

// ---------- fused QKV projection GEMM + RoPE / V^T epilogue ----------
// z=0: Q = Ae@WtQ^T + bQ, rope, *SCALE_L2E -> Qbf [B,H,L,64] bf16
// z=1: K = Ak@WtK^T + bK, rope            -> Kbf [B,H,L,64] bf16
// z=2: V = Ak@WtV^T + bV                  -> Vtr [B*H,64,L] bf16, kv-index
//      pi-permuted (middle quads of each 16-group swapped) so flash PV needs
//      no cross-lane exchange.
__global__ __launch_bounds__(256) void k_gemm_qkv(
    const bf16_t* __restrict__ Ae, const bf16_t* __restrict__ Ak,
    const bf16_t* __restrict__ WtQ, const bf16_t* __restrict__ WtK,
    const bf16_t* __restrict__ WtV, const float* __restrict__ bQ,
    const float* __restrict__ bK, const float* __restrict__ bV,
    const float2* __restrict__ tab, bf16_t* __restrict__ Qbf,
    bf16_t* __restrict__ Kbf, bf16_t* __restrict__ Vtr) {
  constexpr int K = Ev;
  const int z = blockIdx.z;
  const bf16_t* A = (z == 0) ? Ae : Ak;
  const bf16_t* Bt = (z == 0) ? WtQ : (z == 1) ? WtK : WtV;
  const float* bias = (z == 0) ? bQ : (z == 1) ? bK : bV;

  __shared__ __align__(16) bf16_t As[128 * 32];
  __shared__ __align__(16) bf16_t Bs[128 * 32];
  const int tid = threadIdx.x;
  const int wid = tid >> 6, lane = tid & 63;
  const int bm = blockIdx.y * 128, bn = blockIdx.x * 128;
  const int wr = wid >> 1, wc = wid & 1;
  f32x4 acc[4][4] = {};
  const int srow = wid * 32 + (lane >> 2);
  const int scol = (lane & 3) * 8;
  const size_t ga0 = (size_t)(bm + srow) * K + scol;
  const size_t ga1 = (size_t)(bm + srow + 16) * K + scol;
  const size_t gb0 = (size_t)(bn + srow) * K + scol;
  const size_t gb1 = (size_t)(bn + srow + 16) * K + scol;
  bf16_t* asw = &As[wid * 1024];
  bf16_t* bsw = &Bs[wid * 1024];
  for (int k0 = 0; k0 < K; k0 += 32) {
    gload_lds16(A + ga0 + k0, asw);
    gload_lds16(A + ga1 + k0, asw + 512);
    gload_lds16(Bt + gb0 + k0, bsw);
    gload_lds16(Bt + gb1 + k0, bsw + 512);
    __syncthreads();
    bf16x8 af[4], bfr[4];
#pragma unroll
    for (int m = 0; m < 4; m++)
      af[m] = *(const bf16x8*)&As[(wr * 64 + m * 16 + (lane & 15)) * 32 + (lane >> 4) * 8];
#pragma unroll
    for (int n = 0; n < 4; n++)
      bfr[n] = *(const bf16x8*)&Bs[(wc * 64 + n * 16 + (lane & 15)) * 32 + (lane >> 4) * 8];
#pragma unroll
    for (int m = 0; m < 4; m++)
#pragma unroll
      for (int n = 0; n < 4; n++)
        acc[m][n] = __builtin_amdgcn_mfma_f32_16x16x32_bf16(af[m], bfr[n], acc[m][n], 0, 0, 0);
    __syncthreads();
  }

  const int l15 = lane & 15, g = lane >> 4;
  if (z == 2) {
    // V^T direct with pi-permuted kv index (quad-aligned writes)
#pragma unroll
    for (int n = 0; n < 4; n++) {
      const int col = bn + wc * 64 + n * 16 + l15;
      const int hh = (col >> 6) & 15;
      const int d = col & 63;
      const float bv = bias[col];
#pragma unroll
      for (int m = 0; m < 4; m++) {
        const int row0 = bm + wr * 64 + m * 16 + (g << 2);
        const int b = row0 >> 11, l0 = row0 & 2047;
        const int pq = (l0 >> 2) & 3;
        const int pq2 = ((pq & 1) << 1) | (pq >> 1);  // 0,2,1,3
        const int l0p = (l0 & ~12) | (pq2 << 2);
        bf16x4 ov;
#pragma unroll
        for (int r = 0; r < 4; r++) ov[r] = (bf16_t)(acc[m][n][r] + bv);
        *(bf16x4*)&Vtr[((size_t)((b * NHv + hh) * 64 + d)) * Lv + l0p] = ov;
      }
    }
    return;
  }

  // Q/K epilogue: bias + RoPE + (scale) -> bf16 [B,H,L,64]
  bf16_t* Y = (z == 0) ? Qbf : Kbf;
  const float scale = (z == 0) ? SCALE_L2E : 1.0f;
  const float ssign = (l15 & 1) ? 1.0f : -1.0f;
#pragma unroll
  for (int n = 0; n < 4; n++) {
    const int col = bn + wc * 64 + n * 16 + l15;
    const int h = (col >> 6) & 15;
    const int d = col & 63;
    const float bv = bias[col];
    const bool dorope = (d < 32);
    const int ti = d >> 1;
#pragma unroll
    for (int m = 0; m < 4; m++) {
      const int row0 = bm + wr * 64 + m * 16 + (g << 2);
#pragma unroll
      for (int r = 0; r < 4; r++) {
        const int row = row0 + r;
        const int l = row & 2047, b = row >> 11;
        float v = acc[m][n][r] + bv;
        float p = __shfl_xor(v, 1);
        float o = v;
        if (dorope) {
          float2 cs = tab[(l << 4) + ti];
          o = v * cs.x + p * cs.y * ssign;
        }
        Y[(((size_t)(b * NHv + h)) * Lv + l) * 64 + d] = (bf16_t)(o * scale);
      }
    }
  }
}

// ---------- final GEMM: out = AO@WtO^T + bO, f32 ----------
__global__ __launch_bounds__(256) void k_gemm_bt(const bf16_t* __restrict__ A,
                                                 const bf16_t* __restrict__ Bt,
                                                 const float* __restrict__ bias,
                                                 float* __restrict__ C,
                                                 int N, int K) {
  __shared__ __align__(16) bf16_t As[128 * 32];
  __shared__ __align__(16) bf16_t Bs[128 * 32];
  const int tid = threadIdx.x;
  const int wid = tid >> 6, lane = tid & 63;
  const int bm = blockIdx.y * 128, bn = blockIdx.x * 128;
  const int wr = wid >> 1, wc = wid & 1;
  f32x4 acc[4][4] = {};
  const int srow = wid * 32 + (lane >> 2);
  const int scol = (lane & 3) * 8;
  const size_t ga0 = (size_t)(bm + srow) * K + scol;
  const size_t ga1 = (size_t)(bm + srow + 16) * K + scol;
  const size_t gb0 = (size_t)(bn + srow) * K + scol;
  const size_t gb1 = (size_t)(bn + srow + 16) * K + scol;
  bf16_t* asw = &As[wid * 1024];
  bf16_t* bsw = &Bs[wid * 1024];
  for (int k0 = 0; k0 < K; k0 += 32) {
    gload_lds16(A + ga0 + k0, asw);
    gload_lds16(A + ga1 + k0, asw + 512);
    gload_lds16(Bt + gb0 + k0, bsw);
    gload_lds16(Bt + gb1 + k0, bsw + 512);
    __syncthreads();
    bf16x8 af[4], bfr[4];
#pragma unroll
    for (int m = 0; m < 4; m++)
      af[m] = *(const bf16x8*)&As[(wr * 64 + m * 16 + (lane & 15)) * 32 + (lane >> 4) * 8];
#pragma unroll
    for (int n = 0; n < 4; n++)
      bfr[n] = *(const bf16x8*)&Bs[(wc * 64 + n * 16 + (lane & 15)) * 32 + (lane >> 4) * 8];
#pragma unroll
    for (int m = 0; m < 4; m++)
#pragma unroll
      for (int n = 0; n < 4; n++)
        acc[m][n] = __builtin_amdgcn_mfma_f32_16x16x32_bf16(af[m], bfr[n], acc[m][n], 0, 0, 0);
    __syncthreads();
  }
#pragma unroll
  for (int n = 0; n < 4; n++) {
    const int col = bn + wc * 64 + n * 16 + (lane & 15);
    const float bv = bias[col];
#pragma unroll
    for (int m = 0; m < 4; m++) {
      const int row0 = bm + wr * 64 + m * 16 + ((lane >> 4) << 2);
#pragma unroll
      for (int r = 0; r < 4; r++)
        C[(size_t)(row0 + r) * N + col] = acc[m][n][r] + bv;
    }
  }
}

// ---------- mask all-true check (dtype-agnostic: u8-ones OR i32-ones) ----------
__global__ void k_flag_init(int* f) { f[0] = 1; f[1] = 1; }

__global__ __launch_bounds__(256) void k_mask_and(const unsigned int* __restrict__ m,
                                                  int* __restrict__ f, int nwords) {
  int i = blockIdx.x * 256 + threadIdx.x;
  const int u8words = nwords >> 2;
  bool badA = false, badB = false;
  for (; i < nwords; i += gridDim.x * 256) {
    unsigned int v = m[i];
    badA |= (i < u8words) & (v != 0x01010101u);
    badB |= (v != 1u);
  }
  if (__any(badA) && (threadIdx.x & 63) == 0) f[0] = 0;
  if (__any(badB) && (threadIdx.x & 63) == 0) f[1] = 0;
}

// ---------- K tile staging (source-XOR swizzle, linear LDS dest), 128 thr ----------
__device__ __forceinline__ void flash_stage_k(const bf16_t* __restrict__ Kg,
                                              bf16_t* ksb, int tid, int kt) {
#pragma unroll
  for (int i = 0; i < 4; i++) {
    int slot = i * 128 + tid;           // 0..511
    int r = slot >> 3, c = slot & 7;
    int sb = ((c * 16) ^ ((r & 7) << 4)) >> 1;
    bf16_t* dk = ksb + (size_t)(i * 128 + (tid & 64)) * 8;  // wave-uniform base
    gload_lds16(Kg + (size_t)(kt * 64 + r) * 64 + sb, dk);
  }
}

// ---------- flash attention, 32x32 swapped-QK^T, in-register softmax ----------
// grid (LQ/64, B*H), 2 waves x 32 q-rows, KVBLK=64.
// K: LDS double-buffered (prefetch across barrier). V: direct from global
// (pi-permuted Vtr), issued at iteration top, consumed after softmax (T14) —
// latency hides under QK^T + softmax. 1024 blocks -> ~12-16 waves/CU.
__global__ __launch_bounds__(128) void k_flash32(const bf16_t* __restrict__ Qh,
                                                 const bf16_t* __restrict__ Kh,
                                                 const bf16_t* __restrict__ Vtr,
                                                 const int* __restrict__ mask,
                                                 const int* __restrict__ allflag,
                                                 bf16_t* __restrict__ Oh) {
  __shared__ __align__(16) bf16_t Ks[2][64 * 64];  // [kv][d], swizzled
  __shared__ float sw[2][32];                      // per-wave alpha/linv exchange
  const int tid = threadIdx.x, wid = tid >> 6, lane = tid & 63;
  const int l31 = lane & 31, hf = lane >> 5;
  const int qt = blockIdx.x, bh = blockIdx.y;
  const int b = bh >> 4, hd = bh & 15;
  const size_t base = (size_t)bh * Lv * 64;
  const bf16_t* Kg = Kh + base;
  const bf16_t* Vg = Vtr + base + (size_t)l31 * Lv + hf * 8;
  const int allm = allflag[0] | allflag[1];
  const int q = qt * 64 + wid * 32 + l31;  // this lane's softmax q-row

  // Q B-frags (Q pre-scaled by SCALE_L2E)
  bf16x8 bq[4];
#pragma unroll
  for (int s = 0; s < 4; s++)
    bq[s] = *(const bf16x8*)&Qh[base + (size_t)q * 64 + s * 16 + hf * 8];

  // hoisted swizzled LDS element offsets (loop-invariant)
  const int xsw = (l31 & 7) << 4;
  int eo_[4];
#pragma unroll
  for (int s = 0; s < 4; s++) eo_[s] = (((s * 16 + hf * 8) * 2) ^ xsw) >> 1;

  float m_r = -INFINITY, l_p = 0.f;
  f32x16 o0 = {}, o1 = {};

  flash_stage_k(Kg, Ks[0], tid, 0);
  __syncthreads();
  int cur = 0;
  for (int kt = 0; kt < Lv / 64; ++kt) {
    // issue V fragment loads early (consumed after softmax; latency hidden)
    bf16x8 v0[4], v1[4];
    {
      const bf16_t* vt0 = Vg + kt * 64;
#pragma unroll
      for (int s = 0; s < 4; s++) {
        v0[s] = *(const bf16x8*)(vt0 + s * 16);
        v1[s] = *(const bf16x8*)(vt0 + (size_t)32 * Lv + s * 16);
      }
    }
    // prefetch next K tile into the other buffer
    if (kt + 1 < Lv / 64)
      flash_stage_k(Kg, Ks[cur ^ 1], tid, kt + 1);
    const bf16_t* KsC = Ks[cur];

    // S^T = K·Q^T : st0 = kv 0..31, st1 = kv 32..63
    f32x16 st0 = {}, st1 = {};
    __builtin_amdgcn_s_setprio(1);
#pragma unroll
    for (int s = 0; s < 4; s++) {
      bf16x8 k0 = *(const bf16x8*)&KsC[l31 * 64 + eo_[s]];
      bf16x8 k1 = *(const bf16x8*)&KsC[(32 + l31) * 64 + eo_[s]];
      st0 = __builtin_amdgcn_mfma_f32_32x32x16_bf16(k0, bq[s], st0, 0, 0, 0);
      st1 = __builtin_amdgcn_mfma_f32_32x32x16_bf16(k1, bq[s], st1, 0, 0, 0);
    }
    __builtin_amdgcn_s_setprio(0);

    if (!allm) {
      const int* mrow = &mask[(size_t)b * Lv * Lv + (size_t)q * Lv + kt * 64];
#pragma unroll
      for (int r = 0; r < 16; r++) {
        const int kv = (r & 3) + 8 * (r >> 2) + 4 * hf;
        if (!mrow[kv]) st0[r] = -INFINITY;
        if (!mrow[32 + kv]) st1[r] = -INFINITY;
      }
    }

    // defer-max (T13, THR=8 in log2 units)
    float pm = st0[0];
#pragma unroll
    for (int r = 1; r < 16; r++) pm = fmaxf(pm, st0[r]);
#pragma unroll
    for (int r = 0; r < 16; r++) pm = fmaxf(pm, st1[r]);
    if (__any(pm > m_r + 8.0f)) {
      float pmf = fmaxf(pm, __shfl_xor(pm, 32));
      float mn = fmaxf(m_r, pmf);
      float alpha = exp2f(m_r - mn);
      m_r = mn;
      l_p *= alpha;
      if (!hf) sw[wid][l31] = alpha;
      asm volatile("s_waitcnt lgkmcnt(0)" ::: "memory");
      __builtin_amdgcn_sched_barrier(0);
#pragma unroll
      for (int r = 0; r < 16; r++) {
        float a = sw[wid][(r & 3) + 8 * (r >> 2) + 4 * hf];
        o0[r] *= a;
        o1[r] *= a;
      }
    }
    float ps = 0.f;
#pragma unroll
    for (int r = 0; r < 16; r++) {
      float p = exp2f(st0[r] - m_r);
      st0[r] = p;
      ps += p;
    }
#pragma unroll
    for (int r = 0; r < 16; r++) {
      float p = exp2f(st1[r] - m_r);
      st1[r] = p;
      ps += p;
    }
    l_p += ps;

    // pack P to bf16 pairs, natural register order
    unsigned int pk0[8], pk1[8];
#pragma unroll
    for (int i = 0; i < 8; i++) {
      float a0 = st0[2 * i], a1 = st0[2 * i + 1];
      float b0 = st1[2 * i], b1 = st1[2 * i + 1];
      asm("v_cvt_pk_bf16_f32 %0, %1, %2" : "=v"(pk0[i]) : "v"(a0), "v"(a1));
      asm("v_cvt_pk_bf16_f32 %0, %1, %2" : "=v"(pk1[i]) : "v"(b0), "v"(b1));
    }

    // O += P·V, zero-shuffle: A-frag = 4 consecutive pk words per slice
    __builtin_amdgcn_s_setprio(1);
#pragma unroll
    for (int s = 0; s < 4; s++) {
      u32x4 u;
      if (s == 0) {
        u[0] = pk0[0]; u[1] = pk0[1]; u[2] = pk0[2]; u[3] = pk0[3];
      } else if (s == 1) {
        u[0] = pk0[4]; u[1] = pk0[5]; u[2] = pk0[6]; u[3] = pk0[7];
      } else if (s == 2) {
        u[0] = pk1[0]; u[1] = pk1[1]; u[2] = pk1[2]; u[3] = pk1[3];
      } else {
        u[0] = pk1[4]; u[1] = pk1[5]; u[2] = pk1[6]; u[3] = pk1[7];
      }
      bf16x8 pa = __builtin_bit_cast(bf16x8, u);
      o0 = __builtin_amdgcn_mfma_f32_32x32x16_bf16(pa, v0[s], o0, 0, 0, 0);
      o1 = __builtin_amdgcn_mfma_f32_32x32x16_bf16(pa, v1[s], o1, 0, 0, 0);
    }
    __builtin_amdgcn_s_setprio(0);

    __syncthreads();  // K prefetch landed; all waves done reading Ks[cur]
    cur ^= 1;
  }

  // finish l, normalize, store
  float lt = l_p + __shfl_xor(l_p, 32);
  if (!hf) sw[wid][l31] = 1.0f / lt;
  asm volatile("s_waitcnt lgkmcnt(0)" ::: "memory");
  __builtin_amdgcn_sched_barrier(0);
#pragma unroll
  for (int r = 0; r < 16; r++) {
    const int rq = (r & 3) + 8 * (r >> 2) + 4 * hf;
    float inv = sw[wid][rq];
    const int qg = qt * 64 + wid * 32 + rq;
    const size_t off = ((size_t)(b * Lv + qg)) * Ev + hd * 64;
    Oh[off + l31] = (bf16_t)(o0[r] * inv);
    Oh[off + 32 + l31] = (bf16_t)(o1[r] * inv);
  }
}

extern "C" void kernel_launch(void* const* d_in, const int* in_sizes, int n_in,
                              void* d_out, int out_size, void* d_ws, size_t ws_size,
                              hipStream_t stream) {
  const float* embed = (const float*)d_in[0];
  const float* key = (const float*)d_in[1];
  const int* mask = (const int*)d_in[2];
  const float* WQ = (const float*)d_in[3];
  const float* bQ = (const float*)d_in[4];
  const float* WK = (const float*)d_in[5];
  const float* bK = (const float*)d_in[6];
  const float* WV = (const float*)d_in[7];
  const float* bV = (const float*)d_in[8];
  const float* WO = (const float*)d_in[9];
  const float* bO = (const float*)d_in[10];
  float* out = (float*)d_out;
  char* ws = (char*)d_ws;
  const size_t MB = 1024 * 1024;

  bf16_t* Wt = (bf16_t*)(ws);                 // 4 x 1024x1024 bf16 = 8 MB
  bf16_t* Ae = (bf16_t*)(ws + 8 * MB);        // embed bf16; later reused as AO
  bf16_t* Ak = (bf16_t*)(ws + 16 * MB);       // key bf16
  bf16_t* Qbf = (bf16_t*)(ws + 40 * MB);      // [B,H,L,64]
  bf16_t* Kbf = (bf16_t*)(ws + 48 * MB);
  bf16_t* Vtr = (bf16_t*)(ws + 56 * MB);      // V^T [B*H,64,L], pi-permuted kv
  bf16_t* AO = (bf16_t*)(ws + 8 * MB);
  int* flag = (int*)(ws + 64 * MB);
  float2* tab = (float2*)(ws + 65 * MB);      // 2048*16 float2 = 256 KB

  {
    dim3 cg(4096, 1, 2);
    k_cvt2<<<cg, 256, 0, stream>>>(embed, key, Ae, Ak, Mv * Ev / 4);
  }
  {
    dim3 tb(32, 8), tg(32, 32, 4);
    k_twt<<<tg, tb, 0, stream>>>(WQ, WK, WV, WO, Wt, Wt + 1024 * 1024,
                                 Wt + 2 * 1024 * 1024, Wt + 3 * 1024 * 1024);
  }
  k_trig<<<128, 256, 0, stream>>>(tab);
  k_flag_init<<<1, 1, 0, stream>>>(flag);
  k_mask_and<<<2048, 256, 0, stream>>>((const unsigned int*)mask, flag,
                                       Bv * Lv * Lv);

  {
    dim3 gg(8, 32, 3);  // N/128, M/128, {Q,K,V}
    k_gemm_qkv<<<gg, 256, 0, stream>>>(Ae, Ak, Wt, Wt + 1024 * 1024,
                                       Wt + 2 * 1024 * 1024, bQ, bK, bV, tab,
                                       Qbf, Kbf, Vtr);
  }
  {
    dim3 fg(32, 32);  // LQ/64, B*H
    k_flash32<<<fg, 128, 0, stream>>>(Qbf, Kbf, Vtr, mask, flag, AO);
  }
  {
    dim3 gg(8, 32);
    k_gemm_bt<<<gg, 256, 0, stream>>>(AO, Wt + 3 * 1024 * 1024, bO, out, Ev, Ev);
  }
}

// Round 11
// 171.950 us; speedup vs baseline: 1.1035x; 1.1035x over previous
//
#include <hip/hip_runtime.h>
#include <hip/hip_bf16.h>
#include <cstdint>
#include <cstddef>

typedef __bf16 bf16_t;
typedef bf16_t bf16x8 __attribute__((ext_vector_type(8)));
typedef bf16_t bf16x4 __attribute__((ext_vector_type(4)));
typedef bf16_t bf16x2 __attribute__((ext_vector_type(2)));
typedef float f32x4 __attribute__((ext_vector_type(4)));
typedef float f32x16 __attribute__((ext_vector_type(16)));
typedef unsigned int u32x4 __attribute__((ext_vector_type(4)));

namespace {
constexpr int Bv = 2, Lv = 2048, Ev = 1024, NHv = 16;
constexpr int Mv = Bv * Lv;  // 4096
constexpr float SCALE_L2E = 0.03125f * 1.4426950408889634f;  // (1/sqrt(1024)) * log2(e)
}

__device__ __forceinline__ void gload_lds16(const void* g, void* l) {
  __builtin_amdgcn_global_load_lds(
      (const __attribute__((address_space(1))) unsigned int*)g,
      (__attribute__((address_space(3))) unsigned int*)l,
      16, 0, 0);
}

// ---------- elementwise f32 -> bf16 (two tensors via z) ----------
__global__ __launch_bounds__(256) void k_cvt2(const float* __restrict__ x0,
                                              const float* __restrict__ x1,
                                              bf16_t* __restrict__ y0,
                                              bf16_t* __restrict__ y1, int n4) {
  const float* x = blockIdx.z ? x1 : x0;
  bf16_t* y = blockIdx.z ? y1 : y0;
  int i = blockIdx.x * 256 + threadIdx.x;
  if (i < n4) {
    float4 v = reinterpret_cast<const float4*>(x)[i];
    bf16x4 o = {(bf16_t)v.x, (bf16_t)v.y, (bf16_t)v.z, (bf16_t)v.w};
    *reinterpret_cast<bf16x4*>(&y[(size_t)i * 4]) = o;
  }
}

// ---------- transpose 4 weight matrices 1024x1024 f32 -> bf16 [N][K] ----------
__global__ __launch_bounds__(256) void k_twt(const float* w0, const float* w1,
                                             const float* w2, const float* w3,
                                             bf16_t* t0, bf16_t* t1,
                                             bf16_t* t2, bf16_t* t3) {
  const float* W;
  bf16_t* T;
  switch (blockIdx.z) {
    case 0: W = w0; T = t0; break;
    case 1: W = w1; T = t1; break;
    case 2: W = w2; T = t2; break;
    default: W = w3; T = t3; break;
  }
  __shared__ float tile[32][33];
  const int tx = threadIdx.x, ty = threadIdx.y;  // (32,8)
  const int n0 = blockIdx.x * 32, k0 = blockIdx.y * 32;
#pragma unroll
  for (int i = 0; i < 4; i++) {
    int r = ty + i * 8;
    tile[r][tx] = W[(size_t)(k0 + r) * Ev + n0 + tx];
  }
  __syncthreads();
#pragma unroll
  for (int i = 0; i < 4; i++) {
    int r = ty + i * 8;
    T[(size_t)(n0 + r) * Ev + k0 + tx] = (bf16_t)tile[tx][r];
  }
}

// ---------- RoPE trig table: tab[l*16+i] = {cos, sin}(l * 10000^(-i/16)) ----------
__global__ __launch_bounds__(256) void k_trig(float2* __restrict__ tab) {
  int t = blockIdx.x * 256 + threadIdx.x;  // 2048*16
  int i = t & 15, l = t >> 4;
  float inv = exp2f(-13.287712379549449f * (float)i * (1.0f / 16.0f));
  float s, c;
  sincosf((float)l * inv, &s, &c);
  tab[t] = make_float2(c, s);
}

// ---------- fused QKV projection GEMM + RoPE / V^T epilogue ----------
// z=0: Q = Ae@WtQ^T + bQ, rope, *SCALE_L2E -> Qbf [B,H,L,64] bf16
// z=1: K = Ak@WtK^T + bK, rope            -> Kbf [B,H,L,64] bf16
// z=2: V = Ak@WtV^T + bV                  -> Vtr [B*H,64,L] bf16, kv-index
//      pi-permuted (middle quads of each 16-group swapped) so flash PV needs
//      no cross-lane exchange.
__global__ __launch_bounds__(256) void k_gemm_qkv(
    const bf16_t* __restrict__ Ae, const bf16_t* __restrict__ Ak,
    const bf16_t* __restrict__ WtQ, const bf16_t* __restrict__ WtK,
    const bf16_t* __restrict__ WtV, const float* __restrict__ bQ,
    const float* __restrict__ bK, const float* __restrict__ bV,
    const float2* __restrict__ tab, bf16_t* __restrict__ Qbf,
    bf16_t* __restrict__ Kbf, bf16_t* __restrict__ Vtr) {
  constexpr int K = Ev;
  const int z = blockIdx.z;
  const bf16_t* A = (z == 0) ? Ae : Ak;
  const bf16_t* Bt = (z == 0) ? WtQ : (z == 1) ? WtK : WtV;
  const float* bias = (z == 0) ? bQ : (z == 1) ? bK : bV;

  __shared__ __align__(16) bf16_t As[128 * 32];
  __shared__ __align__(16) bf16_t Bs[128 * 32];
  const int tid = threadIdx.x;
  const int wid = tid >> 6, lane = tid & 63;
  const int bm = blockIdx.y * 128, bn = blockIdx.x * 128;
  const int wr = wid >> 1, wc = wid & 1;
  f32x4 acc[4][4] = {};
  const int srow = wid * 32 + (lane >> 2);
  const int scol = (lane & 3) * 8;
  const size_t ga0 = (size_t)(bm + srow) * K + scol;
  const size_t ga1 = (size_t)(bm + srow + 16) * K + scol;
  const size_t gb0 = (size_t)(bn + srow) * K + scol;
  const size_t gb1 = (size_t)(bn + srow + 16) * K + scol;
  bf16_t* asw = &As[wid * 1024];
  bf16_t* bsw = &Bs[wid * 1024];
  for (int k0 = 0; k0 < K; k0 += 32) {
    gload_lds16(A + ga0 + k0, asw);
    gload_lds16(A + ga1 + k0, asw + 512);
    gload_lds16(Bt + gb0 + k0, bsw);
    gload_lds16(Bt + gb1 + k0, bsw + 512);
    __syncthreads();
    bf16x8 af[4], bfr[4];
#pragma unroll
    for (int m = 0; m < 4; m++)
      af[m] = *(const bf16x8*)&As[(wr * 64 + m * 16 + (lane & 15)) * 32 + (lane >> 4) * 8];
#pragma unroll
    for (int n = 0; n < 4; n++)
      bfr[n] = *(const bf16x8*)&Bs[(wc * 64 + n * 16 + (lane & 15)) * 32 + (lane >> 4) * 8];
#pragma unroll
    for (int m = 0; m < 4; m++)
#pragma unroll
      for (int n = 0; n < 4; n++)
        acc[m][n] = __builtin_amdgcn_mfma_f32_16x16x32_bf16(af[m], bfr[n], acc[m][n], 0, 0, 0);
    __syncthreads();
  }

  const int l15 = lane & 15, g = lane >> 4;
  if (z == 2) {
    // V^T direct with pi-permuted kv index (quad-aligned writes)
#pragma unroll
    for (int n = 0; n < 4; n++) {
      const int col = bn + wc * 64 + n * 16 + l15;
      const int hh = (col >> 6) & 15;
      const int d = col & 63;
      const float bv = bias[col];
#pragma unroll
      for (int m = 0; m < 4; m++) {
        const int row0 = bm + wr * 64 + m * 16 + (g << 2);
        const int b = row0 >> 11, l0 = row0 & 2047;
        const int pq = (l0 >> 2) & 3;
        const int pq2 = ((pq & 1) << 1) | (pq >> 1);  // 0,2,1,3
        const int l0p = (l0 & ~12) | (pq2 << 2);
        bf16x4 ov;
#pragma unroll
        for (int r = 0; r < 4; r++) ov[r] = (bf16_t)(acc[m][n][r] + bv);
        *(bf16x4*)&Vtr[((size_t)((b * NHv + hh) * 64 + d)) * Lv + l0p] = ov;
      }
    }
    return;
  }

  // Q/K epilogue: bias + RoPE + (scale) -> bf16 [B,H,L,64]
  bf16_t* Y = (z == 0) ? Qbf : Kbf;
  const float scale = (z == 0) ? SCALE_L2E : 1.0f;
  const float ssign = (l15 & 1) ? 1.0f : -1.0f;
#pragma unroll
  for (int n = 0; n < 4; n++) {
    const int col = bn + wc * 64 + n * 16 + l15;
    const int h = (col >> 6) & 15;
    const int d = col & 63;
    const float bv = bias[col];
    const bool dorope = (d < 32);
    const int ti = d >> 1;
#pragma unroll
    for (int m = 0; m < 4; m++) {
      const int row0 = bm + wr * 64 + m * 16 + (g << 2);
#pragma unroll
      for (int r = 0; r < 4; r++) {
        const int row = row0 + r;
        const int l = row & 2047, b = row >> 11;
        float v = acc[m][n][r] + bv;
        float p = __shfl_xor(v, 1);
        float o = v;
        if (dorope) {
          float2 cs = tab[(l << 4) + ti];
          o = v * cs.x + p * cs.y * ssign;
        }
        Y[(((size_t)(b * NHv + h)) * Lv + l) * 64 + d] = (bf16_t)(o * scale);
      }
    }
  }
}

// ---------- final GEMM: out = AO@WtO^T + bO, f32 ----------
__global__ __launch_bounds__(256) void k_gemm_bt(const bf16_t* __restrict__ A,
                                                 const bf16_t* __restrict__ Bt,
                                                 const float* __restrict__ bias,
                                                 float* __restrict__ C,
                                                 int N, int K) {
  __shared__ __align__(16) bf16_t As[128 * 32];
  __shared__ __align__(16) bf16_t Bs[128 * 32];
  const int tid = threadIdx.x;
  const int wid = tid >> 6, lane = tid & 63;
  const int bm = blockIdx.y * 128, bn = blockIdx.x * 128;
  const int wr = wid >> 1, wc = wid & 1;
  f32x4 acc[4][4] = {};
  const int srow = wid * 32 + (lane >> 2);
  const int scol = (lane & 3) * 8;
  const size_t ga0 = (size_t)(bm + srow) * K + scol;
  const size_t ga1 = (size_t)(bm + srow + 16) * K + scol;
  const size_t gb0 = (size_t)(bn + srow) * K + scol;
  const size_t gb1 = (size_t)(bn + srow + 16) * K + scol;
  bf16_t* asw = &As[wid * 1024];
  bf16_t* bsw = &Bs[wid * 1024];
  for (int k0 = 0; k0 < K; k0 += 32) {
    gload_lds16(A + ga0 + k0, asw);
    gload_lds16(A + ga1 + k0, asw + 512);
    gload_lds16(Bt + gb0 + k0, bsw);
    gload_lds16(Bt + gb1 + k0, bsw + 512);
    __syncthreads();
    bf16x8 af[4], bfr[4];
#pragma unroll
    for (int m = 0; m < 4; m++)
      af[m] = *(const bf16x8*)&As[(wr * 64 + m * 16 + (lane & 15)) * 32 + (lane >> 4) * 8];
#pragma unroll
    for (int n = 0; n < 4; n++)
      bfr[n] = *(const bf16x8*)&Bs[(wc * 64 + n * 16 + (lane & 15)) * 32 + (lane >> 4) * 8];
#pragma unroll
    for (int m = 0; m < 4; m++)
#pragma unroll
      for (int n = 0; n < 4; n++)
        acc[m][n] = __builtin_amdgcn_mfma_f32_16x16x32_bf16(af[m], bfr[n], acc[m][n], 0, 0, 0);
    __syncthreads();
  }
#pragma unroll
  for (int n = 0; n < 4; n++) {
    const int col = bn + wc * 64 + n * 16 + (lane & 15);
    const float bv = bias[col];
#pragma unroll
    for (int m = 0; m < 4; m++) {
      const int row0 = bm + wr * 64 + m * 16 + ((lane >> 4) << 2);
#pragma unroll
      for (int r = 0; r < 4; r++)
        C[(size_t)(row0 + r) * N + col] = acc[m][n][r] + bv;
    }
  }
}

// ---------- mask all-true check (dtype-agnostic: u8-ones OR i32-ones) ----------
__global__ void k_flag_init(int* f) { f[0] = 1; f[1] = 1; }

__global__ __launch_bounds__(256) void k_mask_and(const unsigned int* __restrict__ m,
                                                  int* __restrict__ f, int nwords) {
  int i = blockIdx.x * 256 + threadIdx.x;
  const int u8words = nwords >> 2;
  bool badA = false, badB = false;
  for (; i < nwords; i += gridDim.x * 256) {
    unsigned int v = m[i];
    badA |= (i < u8words) & (v != 0x01010101u);
    badB |= (v != 1u);
  }
  if (__any(badA) && (threadIdx.x & 63) == 0) f[0] = 0;
  if (__any(badB) && (threadIdx.x & 63) == 0) f[1] = 0;
}

// ---------- K/V^T tile staging (source-XOR swizzle, linear LDS dest) ----------
__device__ __forceinline__ void flash_stage(const bf16_t* __restrict__ Kg,
                                            const bf16_t* __restrict__ Vg,
                                            bf16_t* ksb, bf16_t* vsb,
                                            int tid, int kt) {
#pragma unroll
  for (int i = 0; i < 2; i++) {
    int slot = i * 256 + tid;
    int r = slot >> 3, c = slot & 7;
    int sb = ((c * 16) ^ ((r & 7) << 4)) >> 1;
    bf16_t* dk = ksb + (size_t)(i * 256 + (tid & 192)) * 8;
    gload_lds16(Kg + (size_t)(kt * 64 + r) * 64 + sb, dk);
    bf16_t* dv = vsb + (size_t)(i * 256 + (tid & 192)) * 8;
    gload_lds16(Vg + (size_t)r * Lv + kt * 64 + sb, dv);
  }
}

// ---------- flash attention, 32x32 swapped-QK^T, in-register softmax ----------
// grid (B*H, LQ/128): blockIdx.x = bh so all 16 q-tiles of one (b,h) land on
// XCD bh%8 (linear id = bh + 32*qt, 32 % 8 == 0) -> K/V L2-resident per XCD
// (4 bh x 1 MB = 4 MB L2). 4 waves x 32 q-rows, KVBLK=64, LDS double-buffered.
// PV zero-shuffle via pi-permuted Vtr.
__global__ __launch_bounds__(256) void k_flash32(const bf16_t* __restrict__ Qh,
                                                 const bf16_t* __restrict__ Kh,
                                                 const bf16_t* __restrict__ Vtr,
                                                 const int* __restrict__ mask,
                                                 const int* __restrict__ allflag,
                                                 bf16_t* __restrict__ Oh) {
  __shared__ __align__(16) bf16_t Ks[2][64 * 64];  // [kv][d], swizzled
  __shared__ __align__(16) bf16_t Vs[2][64 * 64];  // [d][kv-pi], swizzled
  __shared__ float sw[4][32];                      // per-wave alpha/linv exchange
  const int tid = threadIdx.x, wid = tid >> 6, lane = tid & 63;
  const int l31 = lane & 31, hf = lane >> 5;
  const int bh = blockIdx.x, qt = blockIdx.y;      // T1: bh fastest -> XCD-clustered
  const int b = bh >> 4, hd = bh & 15;
  const size_t base = (size_t)bh * Lv * 64;
  const bf16_t* Kg = Kh + base;
  const bf16_t* Vg = Vtr + base;
  const int allm = allflag[0] | allflag[1];
  const int q = qt * 128 + wid * 32 + l31;  // this lane's softmax q-row

  // Q B-frags (Q pre-scaled by SCALE_L2E)
  bf16x8 bq[4];
#pragma unroll
  for (int s = 0; s < 4; s++)
    bq[s] = *(const bf16x8*)&Qh[base + (size_t)q * 64 + s * 16 + hf * 8];

  // hoisted swizzled LDS element offsets (loop-invariant)
  const int xsw = (l31 & 7) << 4;
  int eo_[4];
#pragma unroll
  for (int s = 0; s < 4; s++) eo_[s] = (((s * 16 + hf * 8) * 2) ^ xsw) >> 1;

  float m_r = -INFINITY, l_p = 0.f;
  f32x16 o0 = {}, o1 = {};

  flash_stage(Kg, Vg, Ks[0], Vs[0], tid, 0);
  __syncthreads();
  int cur = 0;
  for (int kt = 0; kt < Lv / 64; ++kt) {
    if (kt + 1 < Lv / 64)
      flash_stage(Kg, Vg, Ks[cur ^ 1], Vs[cur ^ 1], tid, kt + 1);
    const bf16_t* KsC = Ks[cur];
    const bf16_t* VsC = Vs[cur];

    // S^T = K·Q^T : st0 = kv 0..31, st1 = kv 32..63
    f32x16 st0 = {}, st1 = {};
    __builtin_amdgcn_s_setprio(1);
#pragma unroll
    for (int s = 0; s < 4; s++) {
      bf16x8 k0 = *(const bf16x8*)&KsC[l31 * 64 + eo_[s]];
      bf16x8 k1 = *(const bf16x8*)&KsC[(32 + l31) * 64 + eo_[s]];
      st0 = __builtin_amdgcn_mfma_f32_32x32x16_bf16(k0, bq[s], st0, 0, 0, 0);
      st1 = __builtin_amdgcn_mfma_f32_32x32x16_bf16(k1, bq[s], st1, 0, 0, 0);
    }
    __builtin_amdgcn_s_setprio(0);

    if (!allm) {
      const int* mrow = &mask[(size_t)b * Lv * Lv + (size_t)q * Lv + kt * 64];
#pragma unroll
      for (int r = 0; r < 16; r++) {
        const int kv = (r & 3) + 8 * (r >> 2) + 4 * hf;
        if (!mrow[kv]) st0[r] = -INFINITY;
        if (!mrow[32 + kv]) st1[r] = -INFINITY;
      }
    }

    // defer-max (T13, THR=8 in log2 units)
    float pm = st0[0];
#pragma unroll
    for (int r = 1; r < 16; r++) pm = fmaxf(pm, st0[r]);
#pragma unroll
    for (int r = 0; r < 16; r++) pm = fmaxf(pm, st1[r]);
    if (__any(pm > m_r + 8.0f)) {
      float pmf = fmaxf(pm, __shfl_xor(pm, 32));
      float mn = fmaxf(m_r, pmf);
      float alpha = exp2f(m_r - mn);
      m_r = mn;
      l_p *= alpha;
      if (!hf) sw[wid][l31] = alpha;
      asm volatile("s_waitcnt lgkmcnt(0)" ::: "memory");
      __builtin_amdgcn_sched_barrier(0);
#pragma unroll
      for (int r = 0; r < 16; r++) {
        float a = sw[wid][(r & 3) + 8 * (r >> 2) + 4 * hf];
        o0[r] *= a;
        o1[r] *= a;
      }
    }
    float ps = 0.f;
#pragma unroll
    for (int r = 0; r < 16; r++) {
      float p = exp2f(st0[r] - m_r);
      st0[r] = p;
      ps += p;
    }
#pragma unroll
    for (int r = 0; r < 16; r++) {
      float p = exp2f(st1[r] - m_r);
      st1[r] = p;
      ps += p;
    }
    l_p += ps;

    // pack P to bf16 pairs, natural register order
    unsigned int pk0[8], pk1[8];
#pragma unroll
    for (int i = 0; i < 8; i++) {
      float a0 = st0[2 * i], a1 = st0[2 * i + 1];
      float b0 = st1[2 * i], b1 = st1[2 * i + 1];
      asm("v_cvt_pk_bf16_f32 %0, %1, %2" : "=v"(pk0[i]) : "v"(a0), "v"(a1));
      asm("v_cvt_pk_bf16_f32 %0, %1, %2" : "=v"(pk1[i]) : "v"(b0), "v"(b1));
    }

    // O += P·V, zero-shuffle: A-frag = 4 consecutive pk words per slice
    __builtin_amdgcn_s_setprio(1);
#pragma unroll
    for (int s = 0; s < 4; s++) {
      u32x4 u;
      if (s == 0) {
        u[0] = pk0[0]; u[1] = pk0[1]; u[2] = pk0[2]; u[3] = pk0[3];
      } else if (s == 1) {
        u[0] = pk0[4]; u[1] = pk0[5]; u[2] = pk0[6]; u[3] = pk0[7];
      } else if (s == 2) {
        u[0] = pk1[0]; u[1] = pk1[1]; u[2] = pk1[2]; u[3] = pk1[3];
      } else {
        u[0] = pk1[4]; u[1] = pk1[5]; u[2] = pk1[6]; u[3] = pk1[7];
      }
      bf16x8 pa = __builtin_bit_cast(bf16x8, u);
      bf16x8 v0 = *(const bf16x8*)&VsC[l31 * 64 + eo_[s]];
      bf16x8 v1 = *(const bf16x8*)&VsC[(32 + l31) * 64 + eo_[s]];
      o0 = __builtin_amdgcn_mfma_f32_32x32x16_bf16(pa, v0, o0, 0, 0, 0);
      o1 = __builtin_amdgcn_mfma_f32_32x32x16_bf16(pa, v1, o1, 0, 0, 0);
    }
    __builtin_amdgcn_s_setprio(0);

    __syncthreads();
    cur ^= 1;
  }

  // finish l, normalize, store
  float lt = l_p + __shfl_xor(l_p, 32);
  if (!hf) sw[wid][l31] = 1.0f / lt;
  asm volatile("s_waitcnt lgkmcnt(0)" ::: "memory");
  __builtin_amdgcn_sched_barrier(0);
#pragma unroll
  for (int r = 0; r < 16; r++) {
    const int rq = (r & 3) + 8 * (r >> 2) + 4 * hf;
    float inv = sw[wid][rq];
    const int qg = qt * 128 + wid * 32 + rq;
    const size_t off = ((size_t)(b * Lv + qg)) * Ev + hd * 64;
    Oh[off + l31] = (bf16_t)(o0[r] * inv);
    Oh[off + 32 + l31] = (bf16_t)(o1[r] * inv);
  }
}

extern "C" void kernel_launch(void* const* d_in, const int* in_sizes, int n_in,
                              void* d_out, int out_size, void* d_ws, size_t ws_size,
                              hipStream_t stream) {
  const float* embed = (const float*)d_in[0];
  const float* key = (const float*)d_in[1];
  const int* mask = (const int*)d_in[2];
  const float* WQ = (const float*)d_in[3];
  const float* bQ = (const float*)d_in[4];
  const float* WK = (const float*)d_in[5];
  const float* bK = (const float*)d_in[6];
  const float* WV = (const float*)d_in[7];
  const float* bV = (const float*)d_in[8];
  const float* WO = (const float*)d_in[9];
  const float* bO = (const float*)d_in[10];
  float* out = (float*)d_out;
  char* ws = (char*)d_ws;
  const size_t MB = 1024 * 1024;

  bf16_t* Wt = (bf16_t*)(ws);                 // 4 x 1024x1024 bf16 = 8 MB
  bf16_t* Ae = (bf16_t*)(ws + 8 * MB);        // embed bf16; later reused as AO
  bf16_t* Ak = (bf16_t*)(ws + 16 * MB);       // key bf16
  bf16_t* Qbf = (bf16_t*)(ws + 40 * MB);      // [B,H,L,64]
  bf16_t* Kbf = (bf16_t*)(ws + 48 * MB);
  bf16_t* Vtr = (bf16_t*)(ws + 56 * MB);      // V^T [B*H,64,L], pi-permuted kv
  bf16_t* AO = (bf16_t*)(ws + 8 * MB);
  int* flag = (int*)(ws + 64 * MB);
  float2* tab = (float2*)(ws + 65 * MB);      // 2048*16 float2 = 256 KB

  {
    dim3 cg(4096, 1, 2);
    k_cvt2<<<cg, 256, 0, stream>>>(embed, key, Ae, Ak, Mv * Ev / 4);
  }
  {
    dim3 tb(32, 8), tg(32, 32, 4);
    k_twt<<<tg, tb, 0, stream>>>(WQ, WK, WV, WO, Wt, Wt + 1024 * 1024,
                                 Wt + 2 * 1024 * 1024, Wt + 3 * 1024 * 1024);
  }
  k_trig<<<128, 256, 0, stream>>>(tab);
  k_flag_init<<<1, 1, 0, stream>>>(flag);
  k_mask_and<<<2048, 256, 0, stream>>>((const unsigned int*)mask, flag,
                                       Bv * Lv * Lv);

  {
    dim3 gg(8, 32, 3);  // N/128, M/128, {Q,K,V}
    k_gemm_qkv<<<gg, 256, 0, stream>>>(Ae, Ak, Wt, Wt + 1024 * 1024,
                                       Wt + 2 * 1024 * 1024, bQ, bK, bV, tab,
                                       Qbf, Kbf, Vtr);
  }
  {
    dim3 fg(32, 16);  // (B*H, LQ/128) — bh fastest => XCD-clustered per bh
    k_flash32<<<fg, 256, 0, stream>>>(Qbf, Kbf, Vtr, mask, flag, AO);
  }
  {
    dim3 gg(8, 32);
    k_gemm_bt<<<gg, 256, 0, stream>>>(AO, Wt + 3 * 1024 * 1024, bO, out, Ev, Ev);
  }
}

// Round 12
// 161.845 us; speedup vs baseline: 1.1724x; 1.0624x over previous
//
#include <hip/hip_runtime.h>
#include <hip/hip_bf16.h>
#include <cstdint>
#include <cstddef>

typedef __bf16 bf16_t;
typedef bf16_t bf16x8 __attribute__((ext_vector_type(8)));
typedef bf16_t bf16x4 __attribute__((ext_vector_type(4)));
typedef bf16_t bf16x2 __attribute__((ext_vector_type(2)));
typedef float f32x4 __attribute__((ext_vector_type(4)));
typedef float f32x16 __attribute__((ext_vector_type(16)));
typedef unsigned int u32x4 __attribute__((ext_vector_type(4)));

namespace {
constexpr int Bv = 2, Lv = 2048, Ev = 1024, NHv = 16;
constexpr int Mv = Bv * Lv;  // 4096
constexpr float SCALE_L2E = 0.03125f * 1.4426950408889634f;  // (1/sqrt(1024)) * log2(e)
}

__device__ __forceinline__ void gload_lds16(const void* g, void* l) {
  __builtin_amdgcn_global_load_lds(
      (const __attribute__((address_space(1))) unsigned int*)g,
      (__attribute__((address_space(3))) unsigned int*)l,
      16, 0, 0);
}

// ---------- fused prep: cvt(embed,key) + trig table + mask scan + weight T ----
// block ranges: [0,8192) cvt | [8192,8320) trig | [8320,10368) mask |
// [10368,14464) weight transpose.  `bad` is pre-zeroed via hipMemsetAsync;
// mask sections SET bad[i]=1 on failure (no ordering needed).
__global__ __launch_bounds__(256) void k_prep(
    const float* __restrict__ embed, const float* __restrict__ key,
    bf16_t* __restrict__ Ae, bf16_t* __restrict__ Ak,
    float2* __restrict__ tab, int* __restrict__ bad,
    const unsigned int* __restrict__ m,
    const float* w0, const float* w1, const float* w2, const float* w3,
    bf16_t* t0, bf16_t* t1, bf16_t* t2, bf16_t* t3) {
  const int tid = threadIdx.x;
  int bx = blockIdx.x;
  if (bx < 8192) {
    const float* x = (bx < 4096) ? embed : key;
    bf16_t* y = (bx < 4096) ? Ae : Ak;
    int i = (bx & 4095) * 256 + tid;  // exactly Mv*Ev/4 elements
    float4 v = reinterpret_cast<const float4*>(x)[i];
    bf16x4 o = {(bf16_t)v.x, (bf16_t)v.y, (bf16_t)v.z, (bf16_t)v.w};
    *reinterpret_cast<bf16x4*>(&y[(size_t)i * 4]) = o;
    return;
  }
  bx -= 8192;
  if (bx < 128) {
    int t = bx * 256 + tid;  // 2048*16
    int i = t & 15, l = t >> 4;
    float inv = exp2f(-13.287712379549449f * (float)i * (1.0f / 16.0f));
    float s, c;
    sincosf((float)l * inv, &s, &c);
    tab[t] = make_float2(c, s);
    return;
  }
  bx -= 128;
  if (bx < 2048) {
    const int nwords = Bv * Lv * Lv;
    const int u8words = nwords >> 2;
    int i = bx * 256 + tid;
    bool badA = false, badB = false;
    for (; i < nwords; i += 2048 * 256) {
      unsigned int v = m[i];
      badA |= (i < u8words) & (v != 0x01010101u);
      badB |= (v != 1u);
    }
    if (__any(badA) && (tid & 63) == 0) bad[0] = 1;
    if (__any(badB) && (tid & 63) == 0) bad[1] = 1;
    return;
  }
  bx -= 2048;
  {
    // weight transpose 1024x1024 f32 -> bf16 [N][K], 1024 blocks per matrix
    const int z = bx >> 10, rem = bx & 1023;
    const float* W;
    bf16_t* T;
    switch (z) {
      case 0: W = w0; T = t0; break;
      case 1: W = w1; T = t1; break;
      case 2: W = w2; T = t2; break;
      default: W = w3; T = t3; break;
    }
    __shared__ float tile[32][33];
    const int tx = tid & 31, ty = tid >> 5;  // (32,8)
    const int n0 = (rem & 31) * 32, k0 = (rem >> 5) * 32;
#pragma unroll
    for (int i = 0; i < 4; i++) {
      int r = ty + i * 8;
      tile[r][tx] = W[(size_t)(k0 + r) * Ev + n0 + tx];
    }
    __syncthreads();
#pragma unroll
    for (int i = 0; i < 4; i++) {
      int r = ty + i * 8;
      T[(size_t)(n0 + r) * Ev + k0 + tx] = (bf16_t)tile[tx][r];
    }
  }
}

// ---------- fused QKV projection GEMM + RoPE / V^T epilogue ----------
// z=0: Q = Ae@WtQ^T + bQ, rope, *SCALE_L2E -> Qbf [B,H,L,64] bf16
// z=1: K = Ak@WtK^T + bK, rope            -> Kbf [B,H,L,64] bf16
// z=2: V = Ak@WtV^T + bV                  -> Vtr [B*H,64,L] bf16, kv-index
//      pi-permuted (middle quads of each 16-group swapped) so flash PV needs
//      no cross-lane exchange.
__global__ __launch_bounds__(256) void k_gemm_qkv(
    const bf16_t* __restrict__ Ae, const bf16_t* __restrict__ Ak,
    const bf16_t* __restrict__ WtQ, const bf16_t* __restrict__ WtK,
    const bf16_t* __restrict__ WtV, const float* __restrict__ bQ,
    const float* __restrict__ bK, const float* __restrict__ bV,
    const float2* __restrict__ tab, bf16_t* __restrict__ Qbf,
    bf16_t* __restrict__ Kbf, bf16_t* __restrict__ Vtr) {
  constexpr int K = Ev;
  const int z = blockIdx.z;
  const bf16_t* A = (z == 0) ? Ae : Ak;
  const bf16_t* Bt = (z == 0) ? WtQ : (z == 1) ? WtK : WtV;
  const float* bias = (z == 0) ? bQ : (z == 1) ? bK : bV;

  __shared__ __align__(16) bf16_t As[128 * 32];
  __shared__ __align__(16) bf16_t Bs[128 * 32];
  const int tid = threadIdx.x;
  const int wid = tid >> 6, lane = tid & 63;
  const int bm = blockIdx.y * 128, bn = blockIdx.x * 128;
  const int wr = wid >> 1, wc = wid & 1;
  f32x4 acc[4][4] = {};
  const int srow = wid * 32 + (lane >> 2);
  const int scol = (lane & 3) * 8;
  const size_t ga0 = (size_t)(bm + srow) * K + scol;
  const size_t ga1 = (size_t)(bm + srow + 16) * K + scol;
  const size_t gb0 = (size_t)(bn + srow) * K + scol;
  const size_t gb1 = (size_t)(bn + srow + 16) * K + scol;
  bf16_t* asw = &As[wid * 1024];
  bf16_t* bsw = &Bs[wid * 1024];
  for (int k0 = 0; k0 < K; k0 += 32) {
    gload_lds16(A + ga0 + k0, asw);
    gload_lds16(A + ga1 + k0, asw + 512);
    gload_lds16(Bt + gb0 + k0, bsw);
    gload_lds16(Bt + gb1 + k0, bsw + 512);
    __syncthreads();
    bf16x8 af[4], bfr[4];
#pragma unroll
    for (int m = 0; m < 4; m++)
      af[m] = *(const bf16x8*)&As[(wr * 64 + m * 16 + (lane & 15)) * 32 + (lane >> 4) * 8];
#pragma unroll
    for (int n = 0; n < 4; n++)
      bfr[n] = *(const bf16x8*)&Bs[(wc * 64 + n * 16 + (lane & 15)) * 32 + (lane >> 4) * 8];
#pragma unroll
    for (int m = 0; m < 4; m++)
#pragma unroll
      for (int n = 0; n < 4; n++)
        acc[m][n] = __builtin_amdgcn_mfma_f32_16x16x32_bf16(af[m], bfr[n], acc[m][n], 0, 0, 0);
    __syncthreads();
  }

  const int l15 = lane & 15, g = lane >> 4;
  if (z == 2) {
    // V^T direct with pi-permuted kv index (quad-aligned writes)
#pragma unroll
    for (int n = 0; n < 4; n++) {
      const int col = bn + wc * 64 + n * 16 + l15;
      const int hh = (col >> 6) & 15;
      const int d = col & 63;
      const float bv = bias[col];
#pragma unroll
      for (int m = 0; m < 4; m++) {
        const int row0 = bm + wr * 64 + m * 16 + (g << 2);
        const int b = row0 >> 11, l0 = row0 & 2047;
        const int pq = (l0 >> 2) & 3;
        const int pq2 = ((pq & 1) << 1) | (pq >> 1);  // 0,2,1,3
        const int l0p = (l0 & ~12) | (pq2 << 2);
        bf16x4 ov;
#pragma unroll
        for (int r = 0; r < 4; r++) ov[r] = (bf16_t)(acc[m][n][r] + bv);
        *(bf16x4*)&Vtr[((size_t)((b * NHv + hh) * 64 + d)) * Lv + l0p] = ov;
      }
    }
    return;
  }

  // Q/K epilogue: bias + RoPE + (scale) -> bf16 [B,H,L,64]
  bf16_t* Y = (z == 0) ? Qbf : Kbf;
  const float scale = (z == 0) ? SCALE_L2E : 1.0f;
  const float ssign = (l15 & 1) ? 1.0f : -1.0f;
#pragma unroll
  for (int n = 0; n < 4; n++) {
    const int col = bn + wc * 64 + n * 16 + l15;
    const int h = (col >> 6) & 15;
    const int d = col & 63;
    const float bv = bias[col];
    const bool dorope = (d < 32);
    const int ti = d >> 1;
#pragma unroll
    for (int m = 0; m < 4; m++) {
      const int row0 = bm + wr * 64 + m * 16 + (g << 2);
#pragma unroll
      for (int r = 0; r < 4; r++) {
        const int row = row0 + r;
        const int l = row & 2047, b = row >> 11;
        float v = acc[m][n][r] + bv;
        float p = __shfl_xor(v, 1);
        float o = v;
        if (dorope) {
          float2 cs = tab[(l << 4) + ti];
          o = v * cs.x + p * cs.y * ssign;
        }
        Y[(((size_t)(b * NHv + h)) * Lv + l) * 64 + d] = (bf16_t)(o * scale);
      }
    }
  }
}

// ---------- final GEMM: out = AO@WtO^T + bO, f32. 128x64 tile, 512 blocks ----
__global__ __launch_bounds__(256) void k_gemm_bt(const bf16_t* __restrict__ A,
                                                 const bf16_t* __restrict__ Bt,
                                                 const float* __restrict__ bias,
                                                 float* __restrict__ C,
                                                 int N, int K) {
  __shared__ __align__(16) bf16_t As[128 * 32];
  __shared__ __align__(16) bf16_t Bs[64 * 32];
  const int tid = threadIdx.x;
  const int wid = tid >> 6, lane = tid & 63;
  const int bm = blockIdx.y * 128, bn = blockIdx.x * 64;
  const int wr = wid >> 1, wc = wid & 1;  // wave = 64 rows x 32 cols
  f32x4 acc[4][2] = {};
  const int srowA = wid * 32 + (lane >> 2);
  const int srowB = wid * 16 + (lane >> 2);
  const int scol = (lane & 3) * 8;
  const size_t ga0 = (size_t)(bm + srowA) * K + scol;
  const size_t ga1 = (size_t)(bm + srowA + 16) * K + scol;
  const size_t gb0 = (size_t)(bn + srowB) * K + scol;
  bf16_t* asw = &As[wid * 1024];
  bf16_t* bsw = &Bs[wid * 512];
  for (int k0 = 0; k0 < K; k0 += 32) {
    gload_lds16(A + ga0 + k0, asw);
    gload_lds16(A + ga1 + k0, asw + 512);
    gload_lds16(Bt + gb0 + k0, bsw);
    __syncthreads();
    bf16x8 af[4], bfr[2];
#pragma unroll
    for (int m = 0; m < 4; m++)
      af[m] = *(const bf16x8*)&As[(wr * 64 + m * 16 + (lane & 15)) * 32 + (lane >> 4) * 8];
#pragma unroll
    for (int n = 0; n < 2; n++)
      bfr[n] = *(const bf16x8*)&Bs[(wc * 32 + n * 16 + (lane & 15)) * 32 + (lane >> 4) * 8];
#pragma unroll
    for (int m = 0; m < 4; m++)
#pragma unroll
      for (int n = 0; n < 2; n++)
        acc[m][n] = __builtin_amdgcn_mfma_f32_16x16x32_bf16(af[m], bfr[n], acc[m][n], 0, 0, 0);
    __syncthreads();
  }
#pragma unroll
  for (int n = 0; n < 2; n++) {
    const int col = bn + wc * 32 + n * 16 + (lane & 15);
    const float bv = bias[col];
#pragma unroll
    for (int m = 0; m < 4; m++) {
      const int row0 = bm + wr * 64 + m * 16 + ((lane >> 4) << 2);
#pragma unroll
      for (int r = 0; r < 4; r++)
        C[(size_t)(row0 + r) * N + col] = acc[m][n][r] + bv;
    }
  }
}

// ---------- K/V^T tile staging (source-XOR swizzle, linear LDS dest) ----------
__device__ __forceinline__ void flash_stage(const bf16_t* __restrict__ Kg,
                                            const bf16_t* __restrict__ Vg,
                                            bf16_t* ksb, bf16_t* vsb,
                                            int tid, int kt) {
#pragma unroll
  for (int i = 0; i < 2; i++) {
    int slot = i * 256 + tid;
    int r = slot >> 3, c = slot & 7;
    int sb = ((c * 16) ^ ((r & 7) << 4)) >> 1;
    bf16_t* dk = ksb + (size_t)(i * 256 + (tid & 192)) * 8;
    gload_lds16(Kg + (size_t)(kt * 64 + r) * 64 + sb, dk);
    bf16_t* dv = vsb + (size_t)(i * 256 + (tid & 192)) * 8;
    gload_lds16(Vg + (size_t)r * Lv + kt * 64 + sb, dv);
  }
}

// ---------- flash attention, 32x32 swapped-QK^T, in-register softmax ----------
// grid (B*H, LQ/128): bh fastest -> XCD-clustered (T1). 4 waves x 32 q-rows,
// KVBLK=64, LDS double-buffered. PV zero-shuffle via pi-permuted Vtr.
__global__ __launch_bounds__(256) void k_flash32(const bf16_t* __restrict__ Qh,
                                                 const bf16_t* __restrict__ Kh,
                                                 const bf16_t* __restrict__ Vtr,
                                                 const int* __restrict__ mask,
                                                 const int* __restrict__ bad,
                                                 bf16_t* __restrict__ Oh) {
  __shared__ __align__(16) bf16_t Ks[2][64 * 64];  // [kv][d], swizzled
  __shared__ __align__(16) bf16_t Vs[2][64 * 64];  // [d][kv-pi], swizzled
  __shared__ float sw[4][32];                      // per-wave alpha/linv exchange
  const int tid = threadIdx.x, wid = tid >> 6, lane = tid & 63;
  const int l31 = lane & 31, hf = lane >> 5;
  const int bh = blockIdx.x, qt = blockIdx.y;      // T1: bh fastest
  const int b = bh >> 4, hd = bh & 15;
  const size_t base = (size_t)bh * Lv * 64;
  const bf16_t* Kg = Kh + base;
  const bf16_t* Vg = Vtr + base;
  const int allm = !(bad[0] & bad[1]);  // all-true if either interpretation clean
  const int q = qt * 128 + wid * 32 + l31;  // this lane's softmax q-row

  // Q B-frags (Q pre-scaled by SCALE_L2E)
  bf16x8 bq[4];
#pragma unroll
  for (int s = 0; s < 4; s++)
    bq[s] = *(const bf16x8*)&Qh[base + (size_t)q * 64 + s * 16 + hf * 8];

  // hoisted swizzled LDS element offsets (loop-invariant)
  const int xsw = (l31 & 7) << 4;
  int eo_[4];
#pragma unroll
  for (int s = 0; s < 4; s++) eo_[s] = (((s * 16 + hf * 8) * 2) ^ xsw) >> 1;

  float m_r = -INFINITY, l_p = 0.f;
  f32x16 o0 = {}, o1 = {};

  flash_stage(Kg, Vg, Ks[0], Vs[0], tid, 0);
  __syncthreads();
  int cur = 0;
  for (int kt = 0; kt < Lv / 64; ++kt) {
    if (kt + 1 < Lv / 64)
      flash_stage(Kg, Vg, Ks[cur ^ 1], Vs[cur ^ 1], tid, kt + 1);
    const bf16_t* KsC = Ks[cur];
    const bf16_t* VsC = Vs[cur];

    // S^T = K·Q^T : st0 = kv 0..31, st1 = kv 32..63
    f32x16 st0 = {}, st1 = {};
    __builtin_amdgcn_s_setprio(1);
#pragma unroll
    for (int s = 0; s < 4; s++) {
      bf16x8 k0 = *(const bf16x8*)&KsC[l31 * 64 + eo_[s]];
      bf16x8 k1 = *(const bf16x8*)&KsC[(32 + l31) * 64 + eo_[s]];
      st0 = __builtin_amdgcn_mfma_f32_32x32x16_bf16(k0, bq[s], st0, 0, 0, 0);
      st1 = __builtin_amdgcn_mfma_f32_32x32x16_bf16(k1, bq[s], st1, 0, 0, 0);
    }
    __builtin_amdgcn_s_setprio(0);

    if (!allm) {
      const int* mrow = &mask[(size_t)b * Lv * Lv + (size_t)q * Lv + kt * 64];
#pragma unroll
      for (int r = 0; r < 16; r++) {
        const int kv = (r & 3) + 8 * (r >> 2) + 4 * hf;
        if (!mrow[kv]) st0[r] = -INFINITY;
        if (!mrow[32 + kv]) st1[r] = -INFINITY;
      }
    }

    // defer-max (T13, THR=8 in log2 units); max3-fused reduction (T17)
    float pm = fmaxf(st0[0], st0[1]);
#pragma unroll
    for (int r = 2; r < 16; r += 2) pm = fmaxf(fmaxf(st0[r], st0[r + 1]), pm);
#pragma unroll
    for (int r = 0; r < 16; r += 2) pm = fmaxf(fmaxf(st1[r], st1[r + 1]), pm);
    if (__any(pm > m_r + 8.0f)) {
      float pmf = fmaxf(pm, __shfl_xor(pm, 32));
      float mn = fmaxf(m_r, pmf);
      float alpha = exp2f(m_r - mn);
      m_r = mn;
      l_p *= alpha;
      if (!hf) sw[wid][l31] = alpha;
      asm volatile("s_waitcnt lgkmcnt(0)" ::: "memory");
      __builtin_amdgcn_sched_barrier(0);
#pragma unroll
      for (int r = 0; r < 16; r++) {
        float a = sw[wid][(r & 3) + 8 * (r >> 2) + 4 * hf];
        o0[r] *= a;
        o1[r] *= a;
      }
    }
    float ps = 0.f;
#pragma unroll
    for (int r = 0; r < 16; r++) {
      float p = exp2f(st0[r] - m_r);
      st0[r] = p;
      ps += p;
    }
#pragma unroll
    for (int r = 0; r < 16; r++) {
      float p = exp2f(st1[r] - m_r);
      st1[r] = p;
      ps += p;
    }
    l_p += ps;

    // pack P to bf16 pairs, natural register order
    unsigned int pk0[8], pk1[8];
#pragma unroll
    for (int i = 0; i < 8; i++) {
      float a0 = st0[2 * i], a1 = st0[2 * i + 1];
      float b0 = st1[2 * i], b1 = st1[2 * i + 1];
      asm("v_cvt_pk_bf16_f32 %0, %1, %2" : "=v"(pk0[i]) : "v"(a0), "v"(a1));
      asm("v_cvt_pk_bf16_f32 %0, %1, %2" : "=v"(pk1[i]) : "v"(b0), "v"(b1));
    }

    // O += P·V, zero-shuffle: A-frag = 4 consecutive pk words per slice
    __builtin_amdgcn_s_setprio(1);
#pragma unroll
    for (int s = 0; s < 4; s++) {
      u32x4 u;
      if (s == 0) {
        u[0] = pk0[0]; u[1] = pk0[1]; u[2] = pk0[2]; u[3] = pk0[3];
      } else if (s == 1) {
        u[0] = pk0[4]; u[1] = pk0[5]; u[2] = pk0[6]; u[3] = pk0[7];
      } else if (s == 2) {
        u[0] = pk1[0]; u[1] = pk1[1]; u[2] = pk1[2]; u[3] = pk1[3];
      } else {
        u[0] = pk1[4]; u[1] = pk1[5]; u[2] = pk1[6]; u[3] = pk1[7];
      }
      bf16x8 pa = __builtin_bit_cast(bf16x8, u);
      bf16x8 v0 = *(const bf16x8*)&VsC[l31 * 64 + eo_[s]];
      bf16x8 v1 = *(const bf16x8*)&VsC[(32 + l31) * 64 + eo_[s]];
      o0 = __builtin_amdgcn_mfma_f32_32x32x16_bf16(pa, v0, o0, 0, 0, 0);
      o1 = __builtin_amdgcn_mfma_f32_32x32x16_bf16(pa, v1, o1, 0, 0, 0);
    }
    __builtin_amdgcn_s_setprio(0);

    __syncthreads();
    cur ^= 1;
  }

  // finish l, normalize, store
  float lt = l_p + __shfl_xor(l_p, 32);
  if (!hf) sw[wid][l31] = 1.0f / lt;
  asm volatile("s_waitcnt lgkmcnt(0)" ::: "memory");
  __builtin_amdgcn_sched_barrier(0);
#pragma unroll
  for (int r = 0; r < 16; r++) {
    const int rq = (r & 3) + 8 * (r >> 2) + 4 * hf;
    float inv = sw[wid][rq];
    const int qg = qt * 128 + wid * 32 + rq;
    const size_t off = ((size_t)(b * Lv + qg)) * Ev + hd * 64;
    Oh[off + l31] = (bf16_t)(o0[r] * inv);
    Oh[off + 32 + l31] = (bf16_t)(o1[r] * inv);
  }
}

extern "C" void kernel_launch(void* const* d_in, const int* in_sizes, int n_in,
                              void* d_out, int out_size, void* d_ws, size_t ws_size,
                              hipStream_t stream) {
  const float* embed = (const float*)d_in[0];
  const float* key = (const float*)d_in[1];
  const int* mask = (const int*)d_in[2];
  const float* WQ = (const float*)d_in[3];
  const float* bQ = (const float*)d_in[4];
  const float* WK = (const float*)d_in[5];
  const float* bK = (const float*)d_in[6];
  const float* WV = (const float*)d_in[7];
  const float* bV = (const float*)d_in[8];
  const float* WO = (const float*)d_in[9];
  const float* bO = (const float*)d_in[10];
  float* out = (float*)d_out;
  char* ws = (char*)d_ws;
  const size_t MB = 1024 * 1024;

  bf16_t* Wt = (bf16_t*)(ws);                 // 4 x 1024x1024 bf16 = 8 MB
  bf16_t* Ae = (bf16_t*)(ws + 8 * MB);        // embed bf16; later reused as AO
  bf16_t* Ak = (bf16_t*)(ws + 16 * MB);       // key bf16
  bf16_t* Qbf = (bf16_t*)(ws + 40 * MB);      // [B,H,L,64]
  bf16_t* Kbf = (bf16_t*)(ws + 48 * MB);
  bf16_t* Vtr = (bf16_t*)(ws + 56 * MB);      // V^T [B*H,64,L], pi-permuted kv
  bf16_t* AO = (bf16_t*)(ws + 8 * MB);
  int* bad = (int*)(ws + 64 * MB);
  float2* tab = (float2*)(ws + 65 * MB);      // 2048*16 float2 = 256 KB

  hipMemsetAsync(bad, 0, 2 * sizeof(int), stream);
  k_prep<<<14464, 256, 0, stream>>>(embed, key, Ae, Ak, tab, bad,
                                    (const unsigned int*)mask, WQ, WK, WV, WO,
                                    Wt, Wt + 1024 * 1024, Wt + 2 * 1024 * 1024,
                                    Wt + 3 * 1024 * 1024);

  {
    dim3 gg(8, 32, 3);  // N/128, M/128, {Q,K,V}
    k_gemm_qkv<<<gg, 256, 0, stream>>>(Ae, Ak, Wt, Wt + 1024 * 1024,
                                       Wt + 2 * 1024 * 1024, bQ, bK, bV, tab,
                                       Qbf, Kbf, Vtr);
  }
  {
    dim3 fg(32, 16);  // (B*H, LQ/128) — bh fastest => XCD-clustered per bh
    k_flash32<<<fg, 256, 0, stream>>>(Qbf, Kbf, Vtr, mask, bad, AO);
  }
  {
    dim3 gg(16, 32);  // N/64, M/128 — 512 blocks = 2 blocks/CU
    k_gemm_bt<<<gg, 256, 0, stream>>>(AO, Wt + 3 * 1024 * 1024, bO, out, Ev, Ev);
  }
}